// Round 10
// baseline (506.960 us; speedup 1.0000x reference)
//
#include <hip/hip_runtime.h>

typedef float v2f __attribute__((ext_vector_type(2)));

#define VOCABN 5000
#define EMBD   16
#define HIDN   32
#define GATES  128   // 4*HID
#define BATCH  512
#define SEQT   2048

// Gate pre-scales folded into proj table and rec columns:
//   sigmoid(z) = 1/(1+exp2(S1*z)),  S1 = -log2(e)
//   tanh(z)    = 2/(1+exp2(S2*z))-1, S2 = -2*log2(e)
#define S1f (-1.4426950408889634f)
#define S2f (-2.8853900817779268f)

__device__ __forceinline__ float rcp1p2(float x) {   // 1/(1+2^x)
    return __builtin_amdgcn_rcpf(1.0f + __builtin_amdgcn_exp2f(x));
}

// Gate-split proj table, one v2f per (token, lane):
//   lane l<32  (j=l):    { S1*z_i[j], S2*z_g[j] }
//   lane l>=32 (j=l-32): { S1*z_f[j], S1*z_o[j] }
__global__ __launch_bounds__(64, 1) void build_proj_kernel(
    const float* __restrict__ emb, const float* __restrict__ W,
    const float* __restrict__ bias, v2f* __restrict__ proj2)
{
    const int v = blockIdx.x;
    const int l = threadIdx.x;
    const int j = l & 31;
    const int half = l >> 5;
    const int c0 = j + half * 32;        // i (lower) / f (upper)
    const int c1 = j + 64 + half * 32;   // g (lower) / o (upper)
    const float sc1 = half ? S1f : S2f;

    float e[EMBD];
#pragma unroll
    for (int k = 0; k < EMBD; ++k) e[k] = emb[v * EMBD + k];
    float z0 = bias[c0];
    float z1 = bias[c1];
#pragma unroll
    for (int k = 0; k < EMBD; ++k) {
        z0 = __builtin_fmaf(e[k], W[k * GATES + c0], z0);
        z1 = __builtin_fmaf(e[k], W[k * GATES + c1], z1);
    }
    proj2[(size_t)v * 64 + l] = (v2f){ S1f * z0, sc1 * z1 };
}

// One 64-lane wave per batch row, gates split across halves:
//   lower lane j:  accumulates (i,g) of unit j -> ig, gg; p = ig*gg
//   upper lane j+32: accumulates (f,o); receives p via shfl_xor(32);
//                    computes cn = fg*c + p, hn = og*tanh(cn).
// h and c live in the UPPER half; h-broadcast via v_readlane(hval, 32+k).
// R2 is forced register-resident via an opaque asm pass-through: without it
// the compiler legally re-loads the loop-invariant rec columns from memory
// every iteration (R7 measured VGPR_Count=40 < the 64 needed -> reloads on
// the critical path).
__global__ __launch_bounds__(64, 1) void lstm_scan_kernel(
    const int* __restrict__ tokens, const float* __restrict__ rec,
    const v2f* __restrict__ proj2, float* __restrict__ out)
{
    const int b = blockIdx.x;
    const int l = threadIdx.x;
    const int j = l & 31;
    const int half = l >> 5;
    const int c0 = j + half * 32;
    const int c1 = j + 64 + half * 32;
    const float sc1 = half ? S1f : S2f;

    // Pre-scaled rec columns for this lane's gate pair (64 VGPRs)
    v2f R2[HIDN];
#pragma unroll
    for (int k = 0; k < HIDN; ++k) {
        R2[k] = (v2f){ S1f * rec[k * GATES + c0], sc1 * rec[k * GATES + c1] };
    }
    // Opacity barrier: values can no longer be rematerialized from `rec`,
    // so they must stay in VGPRs for the whole scan.
#pragma unroll
    for (int k = 0; k < HIDN; ++k) {
        asm volatile("" : "+v"(R2[k]));
    }

    const int* __restrict__ trow = tokens + (size_t)b * SEQT;

    float c = 0.0f, hval = 0.0f;

    int tok0 = trow[0];
    int tok1 = trow[1];
    int tok2 = trow[2];
    v2f xz0 = proj2[(size_t)tok0 * 64 + l];
    v2f xz1 = proj2[(size_t)tok1 * 64 + l];

#pragma unroll 2
    for (int t = 0; t < SEQT; ++t) {
        v2f xz2 = proj2[(size_t)tok2 * 64 + l];
        const int t3 = t + 3;
        const int tok3 = trow[t3 < SEQT ? t3 : SEQT - 1];

        // z = xz + h @ rec (this lane's gate pair); 4-way split accumulators
        v2f a0 = xz0;
        v2f a1 = (v2f){0.f, 0.f};
        v2f a2 = (v2f){0.f, 0.f};
        v2f a3 = (v2f){0.f, 0.f};
#pragma unroll
        for (int k = 0; k < HIDN; k += 4) {
            const float h0 = __int_as_float(
                __builtin_amdgcn_readlane(__float_as_int(hval), 32 + k));
            const float h1 = __int_as_float(
                __builtin_amdgcn_readlane(__float_as_int(hval), 32 + k + 1));
            const float h2 = __int_as_float(
                __builtin_amdgcn_readlane(__float_as_int(hval), 32 + k + 2));
            const float h3 = __int_as_float(
                __builtin_amdgcn_readlane(__float_as_int(hval), 32 + k + 3));
            a0 = __builtin_elementwise_fma((v2f){h0, h0}, R2[k],     a0);
            a1 = __builtin_elementwise_fma((v2f){h1, h1}, R2[k + 1], a1);
            a2 = __builtin_elementwise_fma((v2f){h2, h2}, R2[k + 2], a2);
            a3 = __builtin_elementwise_fma((v2f){h3, h3}, R2[k + 3], a3);
        }
        const v2f z = (a0 + a1) + (a2 + a3);

        // activations (shared instruction stream, per-half meaning):
        const float u = rcp1p2(z.x);                    // lower: ig ; upper: fg
        const float w = rcp1p2(z.y);                    // lower: gg'; upper: og
        const float gg = __builtin_fmaf(2.0f, w, -1.0f);// lower: tanh(zg)
        const float p = u * gg;                         // lower: ig*gg
        const float ps = __shfl_xor(p, 32, 64);         // upper <- lower's p

        const float cn = __builtin_fmaf(u, c, ps);      // upper: fg*c + ig*gg
        const float tc = __builtin_fmaf(2.0f, rcp1p2(S2f * cn), -1.0f);
        const float hn = w * tc;                        // upper: og*tanh(cn)

        const bool m = (tok0 != 0);   // wave-uniform
        c    = m ? cn : c;
        hval = m ? hn : hval;

        tok0 = tok1; tok1 = tok2; tok2 = tok3;
        xz0 = xz1; xz1 = xz2;
    }

    if (half) out[(size_t)b * HIDN + j] = hval;
}

extern "C" void kernel_launch(void* const* d_in, const int* in_sizes, int n_in,
                              void* d_out, int out_size, void* d_ws, size_t ws_size,
                              hipStream_t stream)
{
    const int*   tokens = (const int*)d_in[0];
    const float* emb    = (const float*)d_in[1];
    const float* W      = (const float*)d_in[2];
    const float* rec    = (const float*)d_in[3];
    const float* bias   = (const float*)d_in[4];
    float* out = (float*)d_out;
    v2f* proj2 = (v2f*)d_ws;   // VOCABN*64 v2f = 2.56 MB

    hipLaunchKernelGGL(build_proj_kernel, dim3(VOCABN), dim3(64), 0, stream,
                       emb, W, bias, proj2);
    hipLaunchKernelGGL(lstm_scan_kernel, dim3(BATCH), dim3(64), 0, stream,
                       tokens, rec, proj2, out);
}

// Round 11
// 470.222 us; speedup vs baseline: 1.0781x; 1.0781x over previous
//
#include <hip/hip_runtime.h>

typedef float v2f __attribute__((ext_vector_type(2)));
typedef int   v2i __attribute__((ext_vector_type(2)));

#define VOCABN 5000
#define EMBD   16
#define HIDN   32
#define GATES  128   // 4*HID
#define BATCH  512
#define SEQT   2048

// Gate pre-scales folded into proj table and rec columns:
//   sigmoid(z) = 1/(1+exp2(S1*z)),  S1 = -log2(e)
//   tanh(z)    = 2/(1+exp2(S2*z))-1, S2 = -2*log2(e)
#define S1f (-1.4426950408889634f)
#define S2f (-2.8853900817779268f)

__device__ __forceinline__ float rcp1p2(float x) {   // 1/(1+2^x)
    return __builtin_amdgcn_rcpf(1.0f + __builtin_amdgcn_exp2f(x));
}

// Gate-split proj table, one v2f per (token, lane):
//   lane l<32  (j=l):    { S1*z_i[j], S2*z_g[j] }
//   lane l>=32 (j=l-32): { S1*z_f[j], S1*z_o[j] }
__global__ __launch_bounds__(64, 1) void build_proj_kernel(
    const float* __restrict__ emb, const float* __restrict__ W,
    const float* __restrict__ bias, v2f* __restrict__ proj2)
{
    const int v = blockIdx.x;
    const int l = threadIdx.x;
    const int j = l & 31;
    const int half = l >> 5;
    const int c0 = j + half * 32;        // i (lower) / f (upper)
    const int c1 = j + 64 + half * 32;   // g (lower) / o (upper)
    const float sc1 = half ? S1f : S2f;

    float e[EMBD];
#pragma unroll
    for (int k = 0; k < EMBD; ++k) e[k] = emb[v * EMBD + k];
    float z0 = bias[c0];
    float z1 = bias[c1];
#pragma unroll
    for (int k = 0; k < EMBD; ++k) {
        z0 = __builtin_fmaf(e[k], W[k * GATES + c0], z0);
        z1 = __builtin_fmaf(e[k], W[k * GATES + c1], z1);
    }
    proj2[(size_t)v * 64 + l] = (v2f){ S1f * z0, sc1 * z1 };
}

// One 64-lane wave per batch row, gates split across halves:
//   lower lane j:   accumulates (i,g) -> ig, gg; sends p = S2*ig*gg up
//   upper lane j+32: accumulates (f,o); cs_new = fg*cs + p (cs = S2*c,
//                    pre-scaled cell state so tanh needs no leading mul);
//                    hn = og * (2*rcp1p2(cs_new) - 1).
// Cross-half exchange via v_permlane32_swap_b32 (VALU, ~4cy) — the R7
// __shfl_xor was a DS-pipe round-trip (~120cy) fully exposed on the
// single-wave critical path. ZERO DS ops remain in the step loop.
__global__ __launch_bounds__(64, 1) void lstm_scan_kernel(
    const int* __restrict__ tokens, const float* __restrict__ rec,
    const v2f* __restrict__ proj2, float* __restrict__ out)
{
    const int b = blockIdx.x;
    const int l = threadIdx.x;
    const int j = l & 31;
    const int half = l >> 5;
    const int c0 = j + half * 32;
    const int c1 = j + 64 + half * 32;
    const float sc1 = half ? S1f : S2f;

    // Pre-scaled rec columns for this lane's gate pair (64 VGPRs)
    v2f R2[HIDN];
#pragma unroll
    for (int k = 0; k < HIDN; ++k) {
        R2[k] = (v2f){ S1f * rec[k * GATES + c0], sc1 * rec[k * GATES + c1] };
    }

    const int* __restrict__ trow = tokens + (size_t)b * SEQT;

    float cs = 0.0f, hval = 0.0f;   // cs = S2 * c, upper half only

    int tok0 = trow[0];
    int tok1 = trow[1];
    int tok2 = trow[2];
    v2f xz0 = proj2[(size_t)tok0 * 64 + l];
    v2f xz1 = proj2[(size_t)tok1 * 64 + l];

#pragma unroll 2
    for (int t = 0; t < SEQT; ++t) {
        v2f xz2 = proj2[(size_t)tok2 * 64 + l];
        const int t3 = t + 3;
        const int tok3 = trow[t3 < SEQT ? t3 : SEQT - 1];

        // z = xz + h @ rec (this lane's gate pair); 4-way split accumulators
        v2f a0 = xz0;
        v2f a1 = (v2f){0.f, 0.f};
        v2f a2 = (v2f){0.f, 0.f};
        v2f a3 = (v2f){0.f, 0.f};
#pragma unroll
        for (int k = 0; k < HIDN; k += 4) {
            const float h0 = __int_as_float(
                __builtin_amdgcn_readlane(__float_as_int(hval), 32 + k));
            const float h1 = __int_as_float(
                __builtin_amdgcn_readlane(__float_as_int(hval), 32 + k + 1));
            const float h2 = __int_as_float(
                __builtin_amdgcn_readlane(__float_as_int(hval), 32 + k + 2));
            const float h3 = __int_as_float(
                __builtin_amdgcn_readlane(__float_as_int(hval), 32 + k + 3));
            a0 = __builtin_elementwise_fma((v2f){h0, h0}, R2[k],     a0);
            a1 = __builtin_elementwise_fma((v2f){h1, h1}, R2[k + 1], a1);
            a2 = __builtin_elementwise_fma((v2f){h2, h2}, R2[k + 2], a2);
            a3 = __builtin_elementwise_fma((v2f){h3, h3}, R2[k + 3], a3);
        }
        const v2f z = (a0 + a1) + (a2 + a3);

        // activations (shared instruction stream, per-half meaning):
        const float u = rcp1p2(z.x);                     // lower: ig ; upper: fg
        const float w = rcp1p2(z.y);                     // lower: gg'; upper: og
        const float gg = __builtin_fmaf(2.0f, w, -1.0f); // lower: tanh(zg)
        const float p = (S2f * u) * gg;                  // lower: S2*ig*gg

        // VALU cross-half: r[0] = {p.lo, p.lo} -> upper lanes get lower's p
        const v2i pr = __builtin_amdgcn_permlane32_swap(
            __float_as_int(p), __float_as_int(p), false, false);
        const float ps = __int_as_float(pr[0]);

        const float cns = __builtin_fmaf(u, cs, ps);     // upper: S2*(fg*c+ig*gg)
        const float tc = __builtin_fmaf(2.0f, rcp1p2(cns), -1.0f); // tanh(cn)
        const float hn = w * tc;                         // upper: og*tanh(cn)

        const bool m = (tok0 != 0);   // wave-uniform
        cs   = m ? cns : cs;
        hval = m ? hn : hval;

        tok0 = tok1; tok1 = tok2; tok2 = tok3;
        xz0 = xz1; xz1 = xz2;
    }

    if (half) out[(size_t)b * HIDN + j] = hval;
}

extern "C" void kernel_launch(void* const* d_in, const int* in_sizes, int n_in,
                              void* d_out, int out_size, void* d_ws, size_t ws_size,
                              hipStream_t stream)
{
    const int*   tokens = (const int*)d_in[0];
    const float* emb    = (const float*)d_in[1];
    const float* W      = (const float*)d_in[2];
    const float* rec    = (const float*)d_in[3];
    const float* bias   = (const float*)d_in[4];
    float* out = (float*)d_out;
    v2f* proj2 = (v2f*)d_ws;   // VOCABN*64 v2f = 2.56 MB

    hipLaunchKernelGGL(build_proj_kernel, dim3(VOCABN), dim3(64), 0, stream,
                       emb, W, bias, proj2);
    hipLaunchKernelGGL(lstm_scan_kernel, dim3(BATCH), dim3(64), 0, stream,
                       tokens, rec, proj2, out);
}

// Round 13
// 441.932 us; speedup vs baseline: 1.1471x; 1.0640x over previous
//
#include <hip/hip_runtime.h>

typedef float v2f __attribute__((ext_vector_type(2)));
typedef int   v2i __attribute__((ext_vector_type(2)));
typedef int   v8i __attribute__((ext_vector_type(8)));

#define VOCABN 5000
#define EMBD   16
#define HIDN   32
#define GATES  128   // 4*HID
#define BATCH  512
#define SEQT   2048
#define TB     8      // token batch (one s_load_dwordx8)
#define NTB    (SEQT / TB)

// Gate pre-scales folded into proj table and rec columns:
//   sigmoid(z) = 1/(1+exp2(S1*z)),  S1 = -log2(e)
//   tanh(z)    = 2/(1+exp2(S2*z))-1, S2 = -2*log2(e)
#define S1f (-1.4426950408889634f)
#define S2f (-2.8853900817779268f)

__device__ __forceinline__ float rcp1p2(float x) {   // 1/(1+2^x)
    return __builtin_amdgcn_rcpf(1.0f + __builtin_amdgcn_exp2f(x));
}

// Gate-split proj table, one v2f per (token, lane):
//   lane l<32  (j=l):    { S1*z_i[j], S2*z_g[j] }
//   lane l>=32 (j=l-32): { S1*z_f[j], S1*z_o[j] }
__global__ __launch_bounds__(64, 1) void build_proj_kernel(
    const float* __restrict__ emb, const float* __restrict__ W,
    const float* __restrict__ bias, v2f* __restrict__ proj2)
{
    const int v = blockIdx.x;
    const int l = threadIdx.x;
    const int j = l & 31;
    const int half = l >> 5;
    const int c0 = j + half * 32;        // i (lower) / f (upper)
    const int c1 = j + 64 + half * 32;   // g (lower) / o (upper)
    const float sc1 = half ? S1f : S2f;

    float e[EMBD];
#pragma unroll
    for (int k = 0; k < EMBD; ++k) e[k] = emb[v * EMBD + k];
    float z0 = bias[c0];
    float z1 = bias[c1];
#pragma unroll
    for (int k = 0; k < EMBD; ++k) {
        z0 = __builtin_fmaf(e[k], W[k * GATES + c0], z0);
        z1 = __builtin_fmaf(e[k], W[k * GATES + c1], z1);
    }
    proj2[(size_t)v * 64 + l] = (v2f){ S1f * z0, sc1 * z1 };
}

// One 64-lane wave per batch row, gates split across halves (see R9).
// R10/R11: tokens are loaded 8-at-a-time as a uniform v8i
// (s_load_dwordx8), double-buffered one batch ahead, so the SMEM
// lgkmcnt(0) drain waits on a load issued ~8 steps (~3000 cy) earlier
// instead of the same iteration. The previous per-step s_load exposed
// ~200-300 cy of scalar-cache latency EVERY step (the unexplained
// stall: 590 cy step vs ~190 issue + ~150 chain).
__global__ __launch_bounds__(64, 1) void lstm_scan_kernel(
    const int* __restrict__ tokens, const float* __restrict__ rec,
    const v2f* __restrict__ proj2, float* __restrict__ out)
{
    const int b = blockIdx.x;
    const int l = threadIdx.x;
    const int j = l & 31;
    const int half = l >> 5;
    const int c0 = j + half * 32;
    const int c1 = j + 64 + half * 32;
    const float sc1 = half ? S1f : S2f;

    // Pre-scaled rec columns for this lane's gate pair (64 VGPRs)
    v2f R2[HIDN];
#pragma unroll
    for (int k = 0; k < HIDN; ++k) {
        R2[k] = (v2f){ S1f * rec[k * GATES + c0], sc1 * rec[k * GATES + c1] };
    }

    const int* __restrict__ trow = tokens + (size_t)b * SEQT;

    float cs = 0.0f, hval = 0.0f;   // cs = S2 * c (upper half meaningful)

    // token batches, double-buffered (uniform loads -> SGPRs)
    v8i tokb   = *(const v8i*)(trow);
    v8i tokb_n = *(const v8i*)(trow + TB);

    // xz gather pipeline, depth 2
    v2f xz0 = proj2[(size_t)tokb[0] * 64 + l];
    v2f xz1 = proj2[(size_t)tokb[1] * 64 + l];

    for (int tb = 0; tb < NTB; ++tb) {
        // prefetch token batch tb+2 (clamped; used one full batch later)
        const int nb = (tb + 2 < NTB) ? (tb + 2) : (NTB - 1);
        const v8i tokb_nn = *(const v8i*)(trow + nb * TB);

#pragma unroll
        for (int s = 0; s < TB; ++s) {
            // token for step t+2 (static indexing into SGPR batches)
            const int tpre2 = (s < TB - 2) ? tokb[s + 2] : tokb_n[s - (TB - 2)];
            const v2f xz2 = proj2[(size_t)tpre2 * 64 + l];

            // z = xz + h @ rec (this lane's gate pair); 4-way split accs
            v2f a0 = xz0;
            v2f a1 = (v2f){0.f, 0.f};
            v2f a2 = (v2f){0.f, 0.f};
            v2f a3 = (v2f){0.f, 0.f};
#pragma unroll
            for (int k = 0; k < HIDN; k += 4) {
                const float h0 = __int_as_float(
                    __builtin_amdgcn_readlane(__float_as_int(hval), 32 + k));
                const float h1 = __int_as_float(
                    __builtin_amdgcn_readlane(__float_as_int(hval), 32 + k + 1));
                const float h2 = __int_as_float(
                    __builtin_amdgcn_readlane(__float_as_int(hval), 32 + k + 2));
                const float h3 = __int_as_float(
                    __builtin_amdgcn_readlane(__float_as_int(hval), 32 + k + 3));
                a0 = __builtin_elementwise_fma((v2f){h0, h0}, R2[k],     a0);
                a1 = __builtin_elementwise_fma((v2f){h1, h1}, R2[k + 1], a1);
                a2 = __builtin_elementwise_fma((v2f){h2, h2}, R2[k + 2], a2);
                a3 = __builtin_elementwise_fma((v2f){h3, h3}, R2[k + 3], a3);
            }
            const v2f z = (a0 + a1) + (a2 + a3);

            // activations (shared stream, per-half meaning)
            const float u = rcp1p2(z.x);                     // ig / fg
            const float w = rcp1p2(z.y);                     // gg' / og
            const float gg = __builtin_fmaf(2.0f, w, -1.0f); // tanh(zg)
            const float p = (S2f * u) * gg;                  // S2*ig*gg

            const v2i pr = __builtin_amdgcn_permlane32_swap(
                __float_as_int(p), __float_as_int(p), false, false);
            const float ps = __int_as_float(pr[0]);

            const float cns = __builtin_fmaf(u, cs, ps);     // S2*(fg*c+ig*gg)
            const float tc = __builtin_fmaf(2.0f, rcp1p2(cns), -1.0f);
            const float hn = w * tc;                         // og*tanh(cn)

            const bool m = (tokb[s] != 0);   // uniform (SGPR compare)
            cs   = m ? cns : cs;
            hval = m ? hn : hval;

            xz0 = xz1; xz1 = xz2;
        }

        tokb = tokb_n;
        tokb_n = tokb_nn;
    }

    if (half) out[(size_t)b * HIDN + j] = hval;
}

extern "C" void kernel_launch(void* const* d_in, const int* in_sizes, int n_in,
                              void* d_out, int out_size, void* d_ws, size_t ws_size,
                              hipStream_t stream)
{
    const int*   tokens = (const int*)d_in[0];
    const float* emb    = (const float*)d_in[1];
    const float* W      = (const float*)d_in[2];
    const float* rec    = (const float*)d_in[3];
    const float* bias   = (const float*)d_in[4];
    float* out = (float*)d_out;
    v2f* proj2 = (v2f*)d_ws;   // VOCABN*64 v2f = 2.56 MB

    hipLaunchKernelGGL(build_proj_kernel, dim3(VOCABN), dim3(64), 0, stream,
                       emb, W, bias, proj2);
    hipLaunchKernelGGL(lstm_scan_kernel, dim3(BATCH), dim3(64), 0, stream,
                       tokens, rec, proj2, out);
}